// Round 12
// baseline (150.661 us; speedup 1.0000x reference)
//
#include <hip/hip_runtime.h>
#include <math.h>

// MOTIP criterion (R16): 1 frame/block, 512 thr (8 waves). R15 (146.5us,
// kernel <47us) moved spec-LSE to HBM->reg in-wave, overlapping the solver.
// This round: solver-step software prefetch — the next Dijkstra row's LDS
// loads issue as soon as pj1 is known (right after the DPP reduce), hiding
// ~120cy LDS latency under the u/v update VALU work. Identical arithmetic
// order -> matching unchanged, absmax 0.0. Everything else = R15.
// F=128, N=300, M=32, C=2, K1=512.

constexpr int F_FRAMES = 128;
constexpr int N_PRED   = 300;
constexpr int M_TGT    = 32;
constexpr int K_ID     = 512;
constexpr int NSLOT    = 5;     // ceil(300/64) for the wave-0 solver
constexpr int PITCH    = 301;   // LDS row pitch

// ---------- 5-element register-array dynamic access ----------
__device__ __forceinline__ int sel5i(const int a[NSLOT], int s) {
    int r = a[0];
    r = (s == 1) ? a[1] : r;
    r = (s == 2) ? a[2] : r;
    r = (s == 3) ? a[3] : r;
    r = (s == 4) ? a[4] : r;
    return r;
}
__device__ __forceinline__ float sel5f(const float a[NSLOT], int s) {
    float r = a[0];
    r = (s == 1) ? a[1] : r;
    r = (s == 2) ? a[2] : r;
    r = (s == 3) ? a[3] : r;
    r = (s == 4) ? a[4] : r;
    return r;
}
__device__ __forceinline__ void set5i(int a[NSLOT], int s, int val) {
    if (s == 0) a[0] = val;
    if (s == 1) a[1] = val;
    if (s == 2) a[2] = val;
    if (s == 3) a[3] = val;
    if (s == 4) a[4] = val;
}
// monotone float -> uint (order-preserving)
__device__ __forceinline__ unsigned mono32(float x) {
    unsigned b = __float_as_uint(x);
    return b ^ ((b & 0x80000000u) ? 0xFFFFFFFFu : 0x80000000u);
}

// ---------- scalar broadcast helpers (uniform lane index) ----------
__device__ __forceinline__ int readlane_i(int v, int l) {
    return __builtin_amdgcn_readlane(v, l);
}
__device__ __forceinline__ float readlane_f(float v, int l) {
    return __uint_as_float((unsigned)__builtin_amdgcn_readlane((int)__float_as_uint(v), l));
}

// 64-lane min-reduce via DPP (gfx9 row_shr + row_bcast), result broadcast
// through an SGPR. Proven correct on this HW in R6 (absmax 0.0).
__device__ __forceinline__ unsigned wave_min_bcast(unsigned x) {
    unsigned t;
    t = (unsigned)__builtin_amdgcn_update_dpp((int)0xFFFFFFFFu, (int)x, 0x111, 0xF, 0xF, false); // row_shr:1
    x = (t < x) ? t : x;
    t = (unsigned)__builtin_amdgcn_update_dpp((int)0xFFFFFFFFu, (int)x, 0x112, 0xF, 0xF, false); // row_shr:2
    x = (t < x) ? t : x;
    t = (unsigned)__builtin_amdgcn_update_dpp((int)0xFFFFFFFFu, (int)x, 0x114, 0xF, 0xF, false); // row_shr:4
    x = (t < x) ? t : x;
    t = (unsigned)__builtin_amdgcn_update_dpp((int)0xFFFFFFFFu, (int)x, 0x118, 0xF, 0xF, false); // row_shr:8
    x = (t < x) ? t : x;
    t = (unsigned)__builtin_amdgcn_update_dpp((int)0xFFFFFFFFu, (int)x, 0x142, 0xF, 0xF, false); // row_bcast:15
    x = (t < x) ? t : x;
    t = (unsigned)__builtin_amdgcn_update_dpp((int)0xFFFFFFFFu, (int)x, 0x143, 0xF, 0xF, false); // row_bcast:31
    x = (t < x) ? t : x;
    return (unsigned)__builtin_amdgcn_readlane((int)x, 63);
}

// LSE over 512 values held as 8xfloat4 per lane across a 16-lane group.
// 4-level group-local shuffle reduce. Partition proven correct in R11/R13/R14.
__device__ __forceinline__ float lse16(const float4 b[8]) {
    float mx = -INFINITY;
#pragma unroll
    for (int q = 0; q < 8; ++q)
        mx = fmaxf(mx, fmaxf(fmaxf(b[q].x, b[q].y), fmaxf(b[q].z, b[q].w)));
#pragma unroll
    for (int off = 8; off > 0; off >>= 1) mx = fmaxf(mx, __shfl_xor(mx, off));
    float se = 0.f;
#pragma unroll
    for (int q = 0; q < 8; ++q)
        se += expf(b[q].x - mx) + expf(b[q].y - mx) + expf(b[q].z - mx) + expf(b[q].w - mx);
#pragma unroll
    for (int off = 8; off > 0; off >>= 1) se += __shfl_xor(se, off);
    return mx + logf(se);
}

__global__ __launch_bounds__(512) void motip_fused_kernel(
    const float* __restrict__ pl,      // [F,N,2]
    const float* __restrict__ pb,      // [F,N,4]
    const float* __restrict__ il,      // [F,N,K]
    const int*   __restrict__ labels,  // [F,M]
    const float* __restrict__ tb,      // [F,M,4]
    const int*   __restrict__ tids,    // [F,M]
    float* __restrict__ frame_part,    // [F,4] in ws
    int*   __restrict__ counter,       // zeroed by memsetAsync
    float* __restrict__ out)           // [5]
{
    const int f    = blockIdx.x;
    const int tid  = threadIdx.x;
    const int lane = tid & 63;
    const int wave = tid >> 6;

    __shared__ float s_cost[M_TGT * PITCH];
    __shared__ float s_pbox[N_PRED][4];
    __shared__ int   s_claim[N_PRED];
    __shared__ float s_tgt[M_TGT][9];           // cx,cy,w,h,x0,y0,x1,y1,area
    __shared__ int   s_lab[M_TGT];
    __shared__ int   s_tid[M_TGT];
    __shared__ float s_rowval[M_TGT];
    __shared__ int   s_rowarg[M_TGT];
    __shared__ int   s_col4row[M_TGT];
    __shared__ float s_lse[M_TGT];
    __shared__ float s_tgval[M_TGT];
    __shared__ float s_pl1[M_TGT], s_pgi[M_TGT], s_pnl[M_TGT];
    __shared__ int   s_islast;

    // ---- stage A ----
    if (tid < M_TGT) {
        const float4 t4 = ((const float4*)tb)[(size_t)f * M_TGT + tid];
        float cx = t4.x, cy = t4.y, w = t4.z, h = t4.w;
        s_tgt[tid][0] = cx; s_tgt[tid][1] = cy; s_tgt[tid][2] = w; s_tgt[tid][3] = h;
        float x0 = cx - 0.5f * w, y0 = cy - 0.5f * h;
        float x1 = cx + 0.5f * w, y1 = cy + 0.5f * h;
        s_tgt[tid][4] = x0; s_tgt[tid][5] = y0; s_tgt[tid][6] = x1; s_tgt[tid][7] = y1;
        s_tgt[tid][8] = (x1 - x0) * (y1 - y0);
        s_lab[tid] = labels[f * M_TGT + tid];
        s_tid[tid] = tids[f * M_TGT + tid];
    }
    for (int j = tid; j < N_PRED; j += 512) s_claim[j] = 0x7fffffff;

    // one column per thread (512 >= 300)
    float p0 = 0.f, p1 = 0.f, pcx = 0.f, pcy = 0.f, pw = 0.f, ph = 0.f;
    float px0 = 0.f, py0 = 0.f, px1 = 0.f, py1 = 0.f, parea = 0.f;
    if (tid < N_PRED) {
        float2 lg = ((const float2*)pl)[(size_t)f * N_PRED + tid];
        // softmax(2) with one exp, matching max-subtracted reference
        float d  = lg.y - lg.x;
        float e  = expf(-fabsf(d));
        float r  = 1.0f / (1.0f + e);
        float pmax = r, pmin = e * r;
        p0 = (d <= 0.f) ? pmax : pmin;
        p1 = (d <= 0.f) ? pmin : pmax;
        float4 b4 = ((const float4*)pb)[(size_t)f * N_PRED + tid];
        pcx = b4.x; pcy = b4.y; pw = b4.z; ph = b4.w;
        s_pbox[tid][0] = b4.x; s_pbox[tid][1] = b4.y; s_pbox[tid][2] = b4.z; s_pbox[tid][3] = b4.w;
        px0 = b4.x - 0.5f * b4.z; py0 = b4.y - 0.5f * b4.w;
        px1 = b4.x + 0.5f * b4.z; py1 = b4.y + 0.5f * b4.w;
        parea = (px1 - px0) * (py1 - py0);
    }
    __syncthreads();

    // cost fill: C[m][j] = 2*(-prob[label]) + 5*L1 - 2*giou
    if (tid < N_PRED) {
#pragma unroll 4
        for (int m = 0; m < M_TGT; ++m) {
            float tcx = s_tgt[m][0], tcy = s_tgt[m][1], tw = s_tgt[m][2], th = s_tgt[m][3];
            float tx0 = s_tgt[m][4], ty0 = s_tgt[m][5], tx1 = s_tgt[m][6], ty1 = s_tgt[m][7];
            float ta  = s_tgt[m][8];
            int   lab = s_lab[m];
            float ccls = -((lab == 0) ? p0 : p1);
            float cl1  = fabsf(pcx - tcx) + fabsf(pcy - tcy)
                       + fabsf(pw - tw)  + fabsf(ph - th);
            float ltx = fmaxf(px0, tx0), lty = fmaxf(py0, ty0);
            float rbx = fminf(px1, tx1), rby = fminf(py1, ty1);
            float iw = fmaxf(rbx - ltx, 0.f), ih = fmaxf(rby - lty, 0.f);
            float inter = iw * ih;
            float uni   = parea + ta - inter;
            float iou   = inter / uni;
            float Ltx = fminf(px0, tx0), Lty = fminf(py0, ty0);
            float Rbx = fmaxf(px1, tx1), Rby = fmaxf(py1, ty1);
            float cw = fmaxf(Rbx - Ltx, 0.f), ch = fmaxf(Rby - Lty, 0.f);
            float ac = cw * ch;
            float giou = iou - (ac - uni) / ac;
            s_cost[m * PITCH + tid] = 2.f * ccls + 5.f * cl1 - 2.f * giou;
        }
    }
    __syncthreads();

    // greedy init: row minima, 16 threads per row (same argmin semantics:
    // smallest j among equal minima)
    {
        int m = tid >> 4, k = tid & 15;
        float bv = INFINITY; int bj = 0;
        const float* crow = s_cost + m * PITCH;
        for (int j = k; j < N_PRED; j += 16) {
            float c = crow[j];
            if (c < bv) { bv = c; bj = j; }
        }
#pragma unroll
        for (int off = 1; off < 16; off <<= 1) {
            float ov = __shfl_xor(bv, off);
            int   oj = __shfl_xor(bj, off);
            if (ov < bv || (ov == bv && oj < bj)) { bv = ov; bj = oj; }
        }
        if (k == 0) {
            s_rowval[m] = bv;
            s_rowarg[m] = bj;
            s_col4row[m] = bj;      // default (solver overwrites all 32)
            atomicMin(&s_claim[bj], m);
        }
    }
    __syncthreads();

    // ---- stage B: solver (wave 0) ∥ HBM->reg spec-LSE on waves 1-7 ----
    if (wave == 0) {
        int pcol[NSLOT];
#pragma unroll
        for (int s = 0; s < NSLOT; ++s) {
            int j = s * 64 + lane;
            pcol[s] = -1;
            if (j < N_PRED) { int c = s_claim[j]; if (c != 0x7fffffff) pcol[s] = c; }
        }
        float v[NSLOT];
#pragma unroll
        for (int s = 0; s < NSLOT; ++s) v[s] = 0.f;

        float u_reg = 0.f;
        bool assigned = false;
        if (lane < M_TGT) {
            u_reg = s_rowval[lane];
            assigned = (s_claim[s_rowarg[lane]] == lane);
        }
        unsigned freeMask = ~(unsigned)(__ballot(assigned) & 0xFFFFFFFFull);

        while (freeMask) {
            int i = __ffs(freeMask) - 1;
            freeMask &= freeMask - 1;

            float minv[NSLOT]; int way[NSLOT]; int used[NSLOT];
#pragma unroll
            for (int s = 0; s < NSLOT; ++s) { minv[s] = INFINITY; way[s] = -1; used[s] = 0; }
            unsigned treeMask = 0;
            int i0 = i, j0 = -1;

            // preload cost row for the tree root
            float crow_reg[NSLOT];
            {
                const float* cr = s_cost + i0 * PITCH;
#pragma unroll
                for (int s = 0; s < NSLOT; ++s) {
                    int j = s * 64 + lane;
                    crow_reg[s] = (j < N_PRED) ? cr[j] : 0.f;
                }
            }

            for (int guard = 0; guard < 4096; ++guard) {
                treeMask |= 1u << i0;
                float u_i0 = readlane_f(u_reg, i0);          // i0 is wave-uniform
                unsigned bkey = 0xFFFFFFFFu;
#pragma unroll
                for (int s = 0; s < NSLOT; ++s) {
                    int j = s * 64 + lane;
                    if (j < N_PRED && !used[s]) {
                        float cur = crow_reg[s] - u_i0 - v[s];
                        if (cur < minv[s]) { minv[s] = cur; way[s] = j0; }
                        unsigned key = (mono32(minv[s]) & 0xFFFFFE00u) | (unsigned)j;
                        bkey = (key < bkey) ? key : bkey;
                    }
                }
                bkey = wave_min_bcast(bkey);                 // DPP + readlane (SGPR)
                int j1 = bkey & 0x1FF;
                int slot1 = j1 >> 6, lane1 = j1 & 63;
                float delta = readlane_f(sel5f(minv, slot1), lane1);
                int pj1 = readlane_i(sel5i(pcol, slot1), lane1);

                // prefetch next tree row; LDS latency hides under the
                // u/v update VALU work below (u_reg[pj1] is not modified
                // by this step's update: pj1 is not yet in treeMask)
                if (pj1 >= 0) {
                    const float* cr = s_cost + pj1 * PITCH;
#pragma unroll
                    for (int s = 0; s < NSLOT; ++s) {
                        int j = s * 64 + lane;
                        crow_reg[s] = (j < N_PRED) ? cr[j] : 0.f;
                    }
                }

                if (lane < M_TGT && ((treeMask >> lane) & 1)) u_reg += delta;
#pragma unroll
                for (int s = 0; s < NSLOT; ++s) {
                    int j = s * 64 + lane;
                    if (j < N_PRED) { if (used[s]) v[s] -= delta; else minv[s] -= delta; }
                }
                if (lane == lane1) set5i(used, slot1, 1);
                j0 = j1;
                if (pj1 < 0) break;
                i0 = pj1;
            }
            int j = j0;
            while (true) {
                int slot = j >> 6, ln = j & 63;
                int wj = readlane_i(sel5i(way, slot), ln);   // j is wave-uniform
                int newp = (wj < 0) ? i : readlane_i(sel5i(pcol, wj >> 6), wj & 63);
                if (lane == ln) set5i(pcol, slot, newp);
                if (wj < 0) break;
                j = wj;
            }
        }
#pragma unroll
        for (int s = 0; s < NSLOT; ++s) {
            int j = s * 64 + lane;
            if (j < N_PRED && pcol[s] >= 0) s_col4row[pcol[s]] = j;
        }
    } else {
        // waves 1-7: spec-LSE straight from HBM into registers.
        // 28 groups of 16 lanes; group gid handles rows {gid, gid+28}.
        const int g   = lane & 15;                        // lane in group
        const int gid = ((wave - 1) << 2) + (lane >> 4);  // 0..27
#pragma unroll
        for (int pass = 0; pass < 2; ++pass) {
            const int m = gid + pass * 28;
            if (m < M_TGT) {
                const float* base = il + ((size_t)f * N_PRED + s_rowarg[m]) * K_ID;
                const float4* b4 = (const float4*)base;
                float4 buf[8];
#pragma unroll
                for (int q = 0; q < 8; ++q) buf[q] = b4[g + (q << 4)];
                float tg = (g == 0) ? base[s_tid[m]] : 0.f;
                float lse = lse16(buf);
                if (g == 0) { s_lse[m] = lse; s_tgval[m] = tg; }
            }
        }
    }
    __syncthreads();

    // ---- stage C: pair losses (16 threads/pair), reuse speculative LSE ----
    {
        const int m = tid >> 4, k = tid & 15;
        const int idx = s_col4row[m];
        const bool match = (idx == s_rowarg[m]);
        float lse = s_lse[m], tgval = s_tgval[m];

        if (!match) {   // recompute LSE for changed rows (~2/frame), from HBM
            const float* base = il + ((size_t)f * N_PRED + idx) * K_ID;
            const float4* b4 = (const float4*)base + k * 8;   // 32 floats/thread
            float4 c0[8];
#pragma unroll
            for (int q = 0; q < 8; ++q) c0[q] = b4[q];
            float M = -INFINITY;
#pragma unroll
            for (int q = 0; q < 8; ++q)
                M = fmaxf(M, fmaxf(fmaxf(c0[q].x, c0[q].y), fmaxf(c0[q].z, c0[q].w)));
            float S = 0.f;
#pragma unroll
            for (int q = 0; q < 8; ++q)
                S += expf(c0[q].x - M) + expf(c0[q].y - M) + expf(c0[q].z - M) + expf(c0[q].w - M);
#pragma unroll
            for (int off = 1; off < 16; off <<= 1) {
                float oM = __shfl_xor(M, off);
                float oS = __shfl_xor(S, off);
                float Mn = fmaxf(M, oM);
                S = S * expf(M - Mn) + oS * expf(oM - Mn);
                M = Mn;
            }
            lse = M + logf(S);
            if (k == 0) tgval = base[s_tid[m]];
        }

        if (k == 0) {
            float nll = lse - tgval;
            float bcx = s_pbox[idx][0], bcy = s_pbox[idx][1];
            float bw  = s_pbox[idx][2], bh  = s_pbox[idx][3];
            float tcx = s_tgt[m][0], tcy = s_tgt[m][1], tw = s_tgt[m][2], th = s_tgt[m][3];
            float l1 = fabsf(bcx - tcx) + fabsf(bcy - tcy) + fabsf(bw - tw) + fabsf(bh - th);
            float ax0 = bcx - 0.5f * bw, ay0 = bcy - 0.5f * bh;
            float ax1 = bcx + 0.5f * bw, ay1 = bcy + 0.5f * bh;
            float tx0 = s_tgt[m][4], ty0 = s_tgt[m][5], tx1 = s_tgt[m][6], ty1 = s_tgt[m][7];
            float a1 = (ax1 - ax0) * (ay1 - ay0);
            float a2 = s_tgt[m][8];
            float iw = fmaxf(fminf(ax1, tx1) - fmaxf(ax0, tx0), 0.f);
            float ih = fmaxf(fminf(ay1, ty1) - fmaxf(ay0, ty0), 0.f);
            float inter = iw * ih;
            float uni = a1 + a2 - inter;
            float iou = inter / uni;
            float cw = fmaxf(fmaxf(ax1, tx1) - fminf(ax0, tx0), 0.f);
            float ch = fmaxf(fmaxf(ay1, ty1) - fminf(ay0, ty0), 0.f);
            float ac = cw * ch;
            float giou = iou - (ac - uni) / ac;
            s_pl1[m] = l1; s_pgi[m] = giou; s_pnl[m] = nll;
        }
    }
    __syncthreads();

    // ---- stage D: per-frame reduce, release-store, last block finalizes ----
    if (wave == 0) {
        float a = 0.f, b = 0.f, c = 0.f;
        if (lane < M_TGT) { a = s_pl1[lane]; b = s_pgi[lane]; c = s_pnl[lane]; }
#pragma unroll
        for (int off = 32; off > 0; off >>= 1) {
            a += __shfl_xor(a, off);
            b += __shfl_xor(b, off);
            c += __shfl_xor(c, off);
        }
        if (lane == 0) {
            __hip_atomic_store(&frame_part[f * 4 + 0], a, __ATOMIC_RELAXED, __HIP_MEMORY_SCOPE_AGENT);
            __hip_atomic_store(&frame_part[f * 4 + 1], b, __ATOMIC_RELAXED, __HIP_MEMORY_SCOPE_AGENT);
            __hip_atomic_store(&frame_part[f * 4 + 2], c, __ATOMIC_RELAXED, __HIP_MEMORY_SCOPE_AGENT);
            __threadfence();
            int old = atomicAdd(counter, 1);
            s_islast = (old == F_FRAMES - 1) ? 1 : 0;
        }
    }
    __syncthreads();

    if (s_islast) {
        __threadfence();
        float a = 0.f, b = 0.f, c = 0.f;
        if (tid < F_FRAMES) {
            a = __hip_atomic_load(&frame_part[tid * 4 + 0], __ATOMIC_RELAXED, __HIP_MEMORY_SCOPE_AGENT);
            b = __hip_atomic_load(&frame_part[tid * 4 + 1], __ATOMIC_RELAXED, __HIP_MEMORY_SCOPE_AGENT);
            c = __hip_atomic_load(&frame_part[tid * 4 + 2], __ATOMIC_RELAXED, __HIP_MEMORY_SCOPE_AGENT);
        }
#pragma unroll
        for (int off = 32; off > 0; off >>= 1) {
            a += __shfl_xor(a, off);
            b += __shfl_xor(b, off);
            c += __shfl_xor(c, off);
        }
        __shared__ float w[3][2];
        if (lane == 0 && wave < 2) { w[0][wave] = a; w[1][wave] = b; w[2][wave] = c; }
        __syncthreads();
        if (tid == 0) {
            constexpr float P = (float)(F_FRAMES * M_TGT);
            float S0 = w[0][0] + w[0][1];
            float S1 = w[1][0] + w[1][1];
            float S2 = w[2][0] + w[2][1];
            float l1  = S0 / (P * 4.f);
            float gl  = 1.f - S1 / P;
            float idl = S2 / P;
            out[0] = 5.f * l1 + 2.f * gl + 1.f * idl;   // + 2*0 cls
            out[1] = 0.f;
            out[2] = l1;
            out[3] = gl;
            out[4] = idl;
        }
    }
}

extern "C" void kernel_launch(void* const* d_in, const int* in_sizes, int n_in,
                              void* d_out, int out_size, void* d_ws, size_t ws_size,
                              hipStream_t stream) {
    const float* pl     = (const float*)d_in[0];   // pred_logits  [8,16,300,2]
    const float* pb     = (const float*)d_in[1];   // pred_boxes   [8,16,300,4]
    const float* il     = (const float*)d_in[2];   // id_logits    [8,16,300,512]
    const int*   labels = (const int*)d_in[3];     // target_labels [128,32]
    const float* tb     = (const float*)d_in[4];   // target_boxes  [128,32,4]
    const int*   tids   = (const int*)d_in[5];     // target_ids    [128,32]
    float* out = (float*)d_out;

    float* frame_part = (float*)d_ws;                          // [128,4] = 2 KB
    int*   counter    = (int*)((char*)d_ws + 4096);            // 4 B

    hipMemsetAsync(counter, 0, sizeof(int), stream);
    motip_fused_kernel<<<F_FRAMES, 512, 0, stream>>>(
        pl, pb, il, labels, tb, tids, frame_part, counter, out);
}

// Round 13
// 145.355 us; speedup vs baseline: 1.0365x; 1.0365x over previous
//
#include <hip/hip_runtime.h>
#include <math.h>

// MOTIP criterion (R17 = R15 revert): best verified config (146.5us,
// absmax 0.0). R16's solver-row prefetch regressed (+4.2us) and is
// reverted. Final structure: 1 frame/block, 512 thr (8 waves);
// spec-LSE HBM->reg in 16-lane groups on waves 1-7, overlapping the
// R6-proven DPP/readlane JV solver on wave 0; no LDS staging.
// Session ledger: wins = DPP scalarization (R6), 512-thr MLP (R14),
// staging deletion + solver||LSE overlap (R15). Condemned: column-
// reduction warm start (R7/8/9), reg-pipelined LSE (R11), LDS burst
// staging (R13), solver prefetch (R16). Remaining time = ~100us harness
// poison fills + ~46us kernel (serial JV ~15us + cold-cache chains).
// F=128, N=300, M=32, C=2, K1=512.

constexpr int F_FRAMES = 128;
constexpr int N_PRED   = 300;
constexpr int M_TGT    = 32;
constexpr int K_ID     = 512;
constexpr int NSLOT    = 5;     // ceil(300/64) for the wave-0 solver
constexpr int PITCH    = 301;   // LDS row pitch

// ---------- 5-element register-array dynamic access ----------
__device__ __forceinline__ int sel5i(const int a[NSLOT], int s) {
    int r = a[0];
    r = (s == 1) ? a[1] : r;
    r = (s == 2) ? a[2] : r;
    r = (s == 3) ? a[3] : r;
    r = (s == 4) ? a[4] : r;
    return r;
}
__device__ __forceinline__ float sel5f(const float a[NSLOT], int s) {
    float r = a[0];
    r = (s == 1) ? a[1] : r;
    r = (s == 2) ? a[2] : r;
    r = (s == 3) ? a[3] : r;
    r = (s == 4) ? a[4] : r;
    return r;
}
__device__ __forceinline__ void set5i(int a[NSLOT], int s, int val) {
    if (s == 0) a[0] = val;
    if (s == 1) a[1] = val;
    if (s == 2) a[2] = val;
    if (s == 3) a[3] = val;
    if (s == 4) a[4] = val;
}
// monotone float -> uint (order-preserving)
__device__ __forceinline__ unsigned mono32(float x) {
    unsigned b = __float_as_uint(x);
    return b ^ ((b & 0x80000000u) ? 0xFFFFFFFFu : 0x80000000u);
}

// ---------- scalar broadcast helpers (uniform lane index) ----------
__device__ __forceinline__ int readlane_i(int v, int l) {
    return __builtin_amdgcn_readlane(v, l);
}
__device__ __forceinline__ float readlane_f(float v, int l) {
    return __uint_as_float((unsigned)__builtin_amdgcn_readlane((int)__float_as_uint(v), l));
}

// 64-lane min-reduce via DPP (gfx9 row_shr + row_bcast), result broadcast
// through an SGPR. Proven correct on this HW in R6 (absmax 0.0).
__device__ __forceinline__ unsigned wave_min_bcast(unsigned x) {
    unsigned t;
    t = (unsigned)__builtin_amdgcn_update_dpp((int)0xFFFFFFFFu, (int)x, 0x111, 0xF, 0xF, false); // row_shr:1
    x = (t < x) ? t : x;
    t = (unsigned)__builtin_amdgcn_update_dpp((int)0xFFFFFFFFu, (int)x, 0x112, 0xF, 0xF, false); // row_shr:2
    x = (t < x) ? t : x;
    t = (unsigned)__builtin_amdgcn_update_dpp((int)0xFFFFFFFFu, (int)x, 0x114, 0xF, 0xF, false); // row_shr:4
    x = (t < x) ? t : x;
    t = (unsigned)__builtin_amdgcn_update_dpp((int)0xFFFFFFFFu, (int)x, 0x118, 0xF, 0xF, false); // row_shr:8
    x = (t < x) ? t : x;
    t = (unsigned)__builtin_amdgcn_update_dpp((int)0xFFFFFFFFu, (int)x, 0x142, 0xF, 0xF, false); // row_bcast:15
    x = (t < x) ? t : x;
    t = (unsigned)__builtin_amdgcn_update_dpp((int)0xFFFFFFFFu, (int)x, 0x143, 0xF, 0xF, false); // row_bcast:31
    x = (t < x) ? t : x;
    return (unsigned)__builtin_amdgcn_readlane((int)x, 63);
}

// LSE over 512 values held as 8xfloat4 per lane across a 16-lane group.
// 4-level group-local shuffle reduce. Partition proven correct in R11/R13/R14.
__device__ __forceinline__ float lse16(const float4 b[8]) {
    float mx = -INFINITY;
#pragma unroll
    for (int q = 0; q < 8; ++q)
        mx = fmaxf(mx, fmaxf(fmaxf(b[q].x, b[q].y), fmaxf(b[q].z, b[q].w)));
#pragma unroll
    for (int off = 8; off > 0; off >>= 1) mx = fmaxf(mx, __shfl_xor(mx, off));
    float se = 0.f;
#pragma unroll
    for (int q = 0; q < 8; ++q)
        se += expf(b[q].x - mx) + expf(b[q].y - mx) + expf(b[q].z - mx) + expf(b[q].w - mx);
#pragma unroll
    for (int off = 8; off > 0; off >>= 1) se += __shfl_xor(se, off);
    return mx + logf(se);
}

__global__ __launch_bounds__(512) void motip_fused_kernel(
    const float* __restrict__ pl,      // [F,N,2]
    const float* __restrict__ pb,      // [F,N,4]
    const float* __restrict__ il,      // [F,N,K]
    const int*   __restrict__ labels,  // [F,M]
    const float* __restrict__ tb,      // [F,M,4]
    const int*   __restrict__ tids,    // [F,M]
    float* __restrict__ frame_part,    // [F,4] in ws
    int*   __restrict__ counter,       // zeroed by memsetAsync
    float* __restrict__ out)           // [5]
{
    const int f    = blockIdx.x;
    const int tid  = threadIdx.x;
    const int lane = tid & 63;
    const int wave = tid >> 6;

    __shared__ float s_cost[M_TGT * PITCH];
    __shared__ float s_pbox[N_PRED][4];
    __shared__ int   s_claim[N_PRED];
    __shared__ float s_tgt[M_TGT][9];           // cx,cy,w,h,x0,y0,x1,y1,area
    __shared__ int   s_lab[M_TGT];
    __shared__ int   s_tid[M_TGT];
    __shared__ float s_rowval[M_TGT];
    __shared__ int   s_rowarg[M_TGT];
    __shared__ int   s_col4row[M_TGT];
    __shared__ float s_lse[M_TGT];
    __shared__ float s_tgval[M_TGT];
    __shared__ float s_pl1[M_TGT], s_pgi[M_TGT], s_pnl[M_TGT];
    __shared__ int   s_islast;

    // ---- stage A ----
    if (tid < M_TGT) {
        const float4 t4 = ((const float4*)tb)[(size_t)f * M_TGT + tid];
        float cx = t4.x, cy = t4.y, w = t4.z, h = t4.w;
        s_tgt[tid][0] = cx; s_tgt[tid][1] = cy; s_tgt[tid][2] = w; s_tgt[tid][3] = h;
        float x0 = cx - 0.5f * w, y0 = cy - 0.5f * h;
        float x1 = cx + 0.5f * w, y1 = cy + 0.5f * h;
        s_tgt[tid][4] = x0; s_tgt[tid][5] = y0; s_tgt[tid][6] = x1; s_tgt[tid][7] = y1;
        s_tgt[tid][8] = (x1 - x0) * (y1 - y0);
        s_lab[tid] = labels[f * M_TGT + tid];
        s_tid[tid] = tids[f * M_TGT + tid];
    }
    for (int j = tid; j < N_PRED; j += 512) s_claim[j] = 0x7fffffff;

    // one column per thread (512 >= 300)
    float p0 = 0.f, p1 = 0.f, pcx = 0.f, pcy = 0.f, pw = 0.f, ph = 0.f;
    float px0 = 0.f, py0 = 0.f, px1 = 0.f, py1 = 0.f, parea = 0.f;
    if (tid < N_PRED) {
        float2 lg = ((const float2*)pl)[(size_t)f * N_PRED + tid];
        // softmax(2) with one exp, matching max-subtracted reference
        float d  = lg.y - lg.x;
        float e  = expf(-fabsf(d));
        float r  = 1.0f / (1.0f + e);
        float pmax = r, pmin = e * r;
        p0 = (d <= 0.f) ? pmax : pmin;
        p1 = (d <= 0.f) ? pmin : pmax;
        float4 b4 = ((const float4*)pb)[(size_t)f * N_PRED + tid];
        pcx = b4.x; pcy = b4.y; pw = b4.z; ph = b4.w;
        s_pbox[tid][0] = b4.x; s_pbox[tid][1] = b4.y; s_pbox[tid][2] = b4.z; s_pbox[tid][3] = b4.w;
        px0 = b4.x - 0.5f * b4.z; py0 = b4.y - 0.5f * b4.w;
        px1 = b4.x + 0.5f * b4.z; py1 = b4.y + 0.5f * b4.w;
        parea = (px1 - px0) * (py1 - py0);
    }
    __syncthreads();

    // cost fill: C[m][j] = 2*(-prob[label]) + 5*L1 - 2*giou
    if (tid < N_PRED) {
#pragma unroll 4
        for (int m = 0; m < M_TGT; ++m) {
            float tcx = s_tgt[m][0], tcy = s_tgt[m][1], tw = s_tgt[m][2], th = s_tgt[m][3];
            float tx0 = s_tgt[m][4], ty0 = s_tgt[m][5], tx1 = s_tgt[m][6], ty1 = s_tgt[m][7];
            float ta  = s_tgt[m][8];
            int   lab = s_lab[m];
            float ccls = -((lab == 0) ? p0 : p1);
            float cl1  = fabsf(pcx - tcx) + fabsf(pcy - tcy)
                       + fabsf(pw - tw)  + fabsf(ph - th);
            float ltx = fmaxf(px0, tx0), lty = fmaxf(py0, ty0);
            float rbx = fminf(px1, tx1), rby = fminf(py1, ty1);
            float iw = fmaxf(rbx - ltx, 0.f), ih = fmaxf(rby - lty, 0.f);
            float inter = iw * ih;
            float uni   = parea + ta - inter;
            float iou   = inter / uni;
            float Ltx = fminf(px0, tx0), Lty = fminf(py0, ty0);
            float Rbx = fmaxf(px1, tx1), Rby = fmaxf(py1, ty1);
            float cw = fmaxf(Rbx - Ltx, 0.f), ch = fmaxf(Rby - Lty, 0.f);
            float ac = cw * ch;
            float giou = iou - (ac - uni) / ac;
            s_cost[m * PITCH + tid] = 2.f * ccls + 5.f * cl1 - 2.f * giou;
        }
    }
    __syncthreads();

    // greedy init: row minima, 16 threads per row (same argmin semantics:
    // smallest j among equal minima)
    {
        int m = tid >> 4, k = tid & 15;
        float bv = INFINITY; int bj = 0;
        const float* crow = s_cost + m * PITCH;
        for (int j = k; j < N_PRED; j += 16) {
            float c = crow[j];
            if (c < bv) { bv = c; bj = j; }
        }
#pragma unroll
        for (int off = 1; off < 16; off <<= 1) {
            float ov = __shfl_xor(bv, off);
            int   oj = __shfl_xor(bj, off);
            if (ov < bv || (ov == bv && oj < bj)) { bv = ov; bj = oj; }
        }
        if (k == 0) {
            s_rowval[m] = bv;
            s_rowarg[m] = bj;
            s_col4row[m] = bj;      // default (solver overwrites all 32)
            atomicMin(&s_claim[bj], m);
        }
    }
    __syncthreads();

    // ---- stage B: solver (wave 0) ∥ HBM->reg spec-LSE on waves 1-7 ----
    if (wave == 0) {
        int pcol[NSLOT];
#pragma unroll
        for (int s = 0; s < NSLOT; ++s) {
            int j = s * 64 + lane;
            pcol[s] = -1;
            if (j < N_PRED) { int c = s_claim[j]; if (c != 0x7fffffff) pcol[s] = c; }
        }
        float v[NSLOT];
#pragma unroll
        for (int s = 0; s < NSLOT; ++s) v[s] = 0.f;

        float u_reg = 0.f;
        bool assigned = false;
        if (lane < M_TGT) {
            u_reg = s_rowval[lane];
            assigned = (s_claim[s_rowarg[lane]] == lane);
        }
        unsigned freeMask = ~(unsigned)(__ballot(assigned) & 0xFFFFFFFFull);

        while (freeMask) {
            int i = __ffs(freeMask) - 1;
            freeMask &= freeMask - 1;

            float minv[NSLOT]; int way[NSLOT]; int used[NSLOT];
#pragma unroll
            for (int s = 0; s < NSLOT; ++s) { minv[s] = INFINITY; way[s] = -1; used[s] = 0; }
            unsigned treeMask = 0;
            int i0 = i, j0 = -1;

            for (int guard = 0; guard < 4096; ++guard) {
                treeMask |= 1u << i0;
                float u_i0 = readlane_f(u_reg, i0);          // i0 is wave-uniform
                const float* crow2 = s_cost + i0 * PITCH;
                unsigned bkey = 0xFFFFFFFFu;
#pragma unroll
                for (int s = 0; s < NSLOT; ++s) {
                    int j = s * 64 + lane;
                    if (j < N_PRED && !used[s]) {
                        float cur = crow2[j] - u_i0 - v[s];
                        if (cur < minv[s]) { minv[s] = cur; way[s] = j0; }
                        unsigned key = (mono32(minv[s]) & 0xFFFFFE00u) | (unsigned)j;
                        bkey = (key < bkey) ? key : bkey;
                    }
                }
                bkey = wave_min_bcast(bkey);                 // DPP + readlane (SGPR)
                int j1 = bkey & 0x1FF;
                int slot1 = j1 >> 6, lane1 = j1 & 63;
                float delta = readlane_f(sel5f(minv, slot1), lane1);

                if (lane < M_TGT && ((treeMask >> lane) & 1)) u_reg += delta;
#pragma unroll
                for (int s = 0; s < NSLOT; ++s) {
                    int j = s * 64 + lane;
                    if (j < N_PRED) { if (used[s]) v[s] -= delta; else minv[s] -= delta; }
                }
                int pj1 = readlane_i(sel5i(pcol, slot1), lane1);
                if (lane == lane1) set5i(used, slot1, 1);
                j0 = j1;
                if (pj1 < 0) break;
                i0 = pj1;
            }
            int j = j0;
            while (true) {
                int slot = j >> 6, ln = j & 63;
                int wj = readlane_i(sel5i(way, slot), ln);   // j is wave-uniform
                int newp = (wj < 0) ? i : readlane_i(sel5i(pcol, wj >> 6), wj & 63);
                if (lane == ln) set5i(pcol, slot, newp);
                if (wj < 0) break;
                j = wj;
            }
        }
#pragma unroll
        for (int s = 0; s < NSLOT; ++s) {
            int j = s * 64 + lane;
            if (j < N_PRED && pcol[s] >= 0) s_col4row[pcol[s]] = j;
        }
    } else {
        // waves 1-7: spec-LSE straight from HBM into registers.
        // 28 groups of 16 lanes; group gid handles rows {gid, gid+28}.
        // Lanes of a wave are lockstep -> a group's loads are complete
        // before its own reduce; no block barrier needed.
        const int g   = lane & 15;                        // lane in group
        const int gid = ((wave - 1) << 2) + (lane >> 4);  // 0..27
#pragma unroll
        for (int pass = 0; pass < 2; ++pass) {
            const int m = gid + pass * 28;
            if (m < M_TGT) {
                const float* base = il + ((size_t)f * N_PRED + s_rowarg[m]) * K_ID;
                const float4* b4 = (const float4*)base;
                float4 buf[8];
#pragma unroll
                for (int q = 0; q < 8; ++q) buf[q] = b4[g + (q << 4)];
                float tg = (g == 0) ? base[s_tid[m]] : 0.f;
                float lse = lse16(buf);
                if (g == 0) { s_lse[m] = lse; s_tgval[m] = tg; }
            }
        }
    }
    __syncthreads();

    // ---- stage C: pair losses (16 threads/pair), reuse speculative LSE ----
    {
        const int m = tid >> 4, k = tid & 15;
        const int idx = s_col4row[m];
        const bool match = (idx == s_rowarg[m]);
        float lse = s_lse[m], tgval = s_tgval[m];

        if (!match) {   // recompute LSE for changed rows (~2/frame), from HBM
            const float* base = il + ((size_t)f * N_PRED + idx) * K_ID;
            const float4* b4 = (const float4*)base + k * 8;   // 32 floats/thread
            float4 c0[8];
#pragma unroll
            for (int q = 0; q < 8; ++q) c0[q] = b4[q];
            float M = -INFINITY;
#pragma unroll
            for (int q = 0; q < 8; ++q)
                M = fmaxf(M, fmaxf(fmaxf(c0[q].x, c0[q].y), fmaxf(c0[q].z, c0[q].w)));
            float S = 0.f;
#pragma unroll
            for (int q = 0; q < 8; ++q)
                S += expf(c0[q].x - M) + expf(c0[q].y - M) + expf(c0[q].z - M) + expf(c0[q].w - M);
#pragma unroll
            for (int off = 1; off < 16; off <<= 1) {
                float oM = __shfl_xor(M, off);
                float oS = __shfl_xor(S, off);
                float Mn = fmaxf(M, oM);
                S = S * expf(M - Mn) + oS * expf(oM - Mn);
                M = Mn;
            }
            lse = M + logf(S);
            if (k == 0) tgval = base[s_tid[m]];
        }

        if (k == 0) {
            float nll = lse - tgval;
            float bcx = s_pbox[idx][0], bcy = s_pbox[idx][1];
            float bw  = s_pbox[idx][2], bh  = s_pbox[idx][3];
            float tcx = s_tgt[m][0], tcy = s_tgt[m][1], tw = s_tgt[m][2], th = s_tgt[m][3];
            float l1 = fabsf(bcx - tcx) + fabsf(bcy - tcy) + fabsf(bw - tw) + fabsf(bh - th);
            float ax0 = bcx - 0.5f * bw, ay0 = bcy - 0.5f * bh;
            float ax1 = bcx + 0.5f * bw, ay1 = bcy + 0.5f * bh;
            float tx0 = s_tgt[m][4], ty0 = s_tgt[m][5], tx1 = s_tgt[m][6], ty1 = s_tgt[m][7];
            float a1 = (ax1 - ax0) * (ay1 - ay0);
            float a2 = s_tgt[m][8];
            float iw = fmaxf(fminf(ax1, tx1) - fmaxf(ax0, tx0), 0.f);
            float ih = fmaxf(fminf(ay1, ty1) - fmaxf(ay0, ty0), 0.f);
            float inter = iw * ih;
            float uni = a1 + a2 - inter;
            float iou = inter / uni;
            float cw = fmaxf(fmaxf(ax1, tx1) - fminf(ax0, tx0), 0.f);
            float ch = fmaxf(fmaxf(ay1, ty1) - fminf(ay0, ty0), 0.f);
            float ac = cw * ch;
            float giou = iou - (ac - uni) / ac;
            s_pl1[m] = l1; s_pgi[m] = giou; s_pnl[m] = nll;
        }
    }
    __syncthreads();

    // ---- stage D: per-frame reduce, release-store, last block finalizes ----
    if (wave == 0) {
        float a = 0.f, b = 0.f, c = 0.f;
        if (lane < M_TGT) { a = s_pl1[lane]; b = s_pgi[lane]; c = s_pnl[lane]; }
#pragma unroll
        for (int off = 32; off > 0; off >>= 1) {
            a += __shfl_xor(a, off);
            b += __shfl_xor(b, off);
            c += __shfl_xor(c, off);
        }
        if (lane == 0) {
            __hip_atomic_store(&frame_part[f * 4 + 0], a, __ATOMIC_RELAXED, __HIP_MEMORY_SCOPE_AGENT);
            __hip_atomic_store(&frame_part[f * 4 + 1], b, __ATOMIC_RELAXED, __HIP_MEMORY_SCOPE_AGENT);
            __hip_atomic_store(&frame_part[f * 4 + 2], c, __ATOMIC_RELAXED, __HIP_MEMORY_SCOPE_AGENT);
            __threadfence();
            int old = atomicAdd(counter, 1);
            s_islast = (old == F_FRAMES - 1) ? 1 : 0;
        }
    }
    __syncthreads();

    if (s_islast) {
        __threadfence();
        float a = 0.f, b = 0.f, c = 0.f;
        if (tid < F_FRAMES) {
            a = __hip_atomic_load(&frame_part[tid * 4 + 0], __ATOMIC_RELAXED, __HIP_MEMORY_SCOPE_AGENT);
            b = __hip_atomic_load(&frame_part[tid * 4 + 1], __ATOMIC_RELAXED, __HIP_MEMORY_SCOPE_AGENT);
            c = __hip_atomic_load(&frame_part[tid * 4 + 2], __ATOMIC_RELAXED, __HIP_MEMORY_SCOPE_AGENT);
        }
#pragma unroll
        for (int off = 32; off > 0; off >>= 1) {
            a += __shfl_xor(a, off);
            b += __shfl_xor(b, off);
            c += __shfl_xor(c, off);
        }
        __shared__ float w[3][2];
        if (lane == 0 && wave < 2) { w[0][wave] = a; w[1][wave] = b; w[2][wave] = c; }
        __syncthreads();
        if (tid == 0) {
            constexpr float P = (float)(F_FRAMES * M_TGT);
            float S0 = w[0][0] + w[0][1];
            float S1 = w[1][0] + w[1][1];
            float S2 = w[2][0] + w[2][1];
            float l1  = S0 / (P * 4.f);
            float gl  = 1.f - S1 / P;
            float idl = S2 / P;
            out[0] = 5.f * l1 + 2.f * gl + 1.f * idl;   // + 2*0 cls
            out[1] = 0.f;
            out[2] = l1;
            out[3] = gl;
            out[4] = idl;
        }
    }
}

extern "C" void kernel_launch(void* const* d_in, const int* in_sizes, int n_in,
                              void* d_out, int out_size, void* d_ws, size_t ws_size,
                              hipStream_t stream) {
    const float* pl     = (const float*)d_in[0];   // pred_logits  [8,16,300,2]
    const float* pb     = (const float*)d_in[1];   // pred_boxes   [8,16,300,4]
    const float* il     = (const float*)d_in[2];   // id_logits    [8,16,300,512]
    const int*   labels = (const int*)d_in[3];     // target_labels [128,32]
    const float* tb     = (const float*)d_in[4];   // target_boxes  [128,32,4]
    const int*   tids   = (const int*)d_in[5];     // target_ids    [128,32]
    float* out = (float*)d_out;

    float* frame_part = (float*)d_ws;                          // [128,4] = 2 KB
    int*   counter    = (int*)((char*)d_ws + 4096);            // 4 B

    hipMemsetAsync(counter, 0, sizeof(int), stream);
    motip_fused_kernel<<<F_FRAMES, 512, 0, stream>>>(
        pl, pb, il, labels, tb, tids, frame_part, counter, out);
}